// Round 1
// baseline (8681.650 us; speedup 1.0000x reference)
//
#include <hip/hip_runtime.h>
#include <math.h>

// Problem constants (match reference)
#define IN_CH  256
#define OUT_CH 256
#define KK     3
#define WDIM   512
#define BATCH  16
#define HH     128

// Conv kernel tiling
#define TILE_H 32
#define TILE_W 64
#define OCB    8     // output channels per block
#define ICH    4     // input channels staged per iteration
#define XS_COLS 66   // logical halo cols (TILE_W + 2)
#define XS_STRIDE 68 // padded to keep rows 16B-aligned; bank-checked
#define XS_ROWS 34   // TILE_H + 2
#define WSTRIDE 12   // 9 weights padded to 12 floats (48B, 16B-aligned)

// ---------------------------------------------------------------------------
// Kernel 1: style[b][i] = sum_j w[b,j] * mod_weight[i,j] * mod_scale + bias[i]
// ---------------------------------------------------------------------------
__global__ void style_kernel(const float* __restrict__ w,
                             const float* __restrict__ mod_weight,
                             const float* __restrict__ mod_bias,
                             float* __restrict__ style) {
    const int b = blockIdx.x;   // 16
    const int i = threadIdx.x;  // 256
    __shared__ float wsh[WDIM];
    for (int j = threadIdx.x; j < WDIM; j += 256) wsh[j] = w[b * WDIM + j];
    __syncthreads();
    const float mod_scale = 1.0f / sqrtf((float)WDIM);
    float acc = 0.f;
    const float* mwp = mod_weight + (size_t)i * WDIM;
    for (int j = 0; j < WDIM; ++j) acc += wsh[j] * mwp[j];
    style[b * IN_CH + i] = acc * mod_scale + mod_bias[i];
}

// ---------------------------------------------------------------------------
// Kernel 2: d[b][o] = rsqrt( conv_scale^2 * sum_i style[b,i]^2 * sum_r w[o,i,r]^2 + 1e-8 )
// ---------------------------------------------------------------------------
__global__ void demod_kernel(const float* __restrict__ weight,
                             const float* __restrict__ style,
                             float* __restrict__ dfac) {
    const int b = blockIdx.x;   // 16
    const int o = threadIdx.x;  // 256
    __shared__ float s2[IN_CH];
    for (int j = threadIdx.x; j < IN_CH; j += 256) {
        float s = style[b * IN_CH + j];
        s2[j] = s * s;
    }
    __syncthreads();
    const float conv_scale2 = 1.0f / (float)(IN_CH * KK * KK);
    float acc = 0.f;
    const float* wp = weight + (size_t)o * IN_CH * 9;
    for (int i = 0; i < IN_CH; ++i) {
        float sq = 0.f;
#pragma unroll
        for (int r = 0; r < 9; ++r) { float v = wp[i * 9 + r]; sq += v * v; }
        acc += sq * s2[i];
    }
    dfac[b * OUT_CH + o] = rsqrtf(acc * conv_scale2 + 1e-8f);
}

// ---------------------------------------------------------------------------
// Kernel 3: direct conv. Block: 256 threads -> 8 oc x (32 x 64) spatial tile.
// Thread (ty=t>>3, tx=t&7): 1 row x 8 cols x 8 oc = 64 accumulators.
// ---------------------------------------------------------------------------
__global__ __launch_bounds__(256, 3) void conv_kernel(
        const float* __restrict__ x,
        const float* __restrict__ weight,
        const float* __restrict__ style,
        const float* __restrict__ dfac,
        float* __restrict__ out) {
    __shared__ float xs[ICH][XS_ROWS * XS_STRIDE];
    __shared__ float wmod[ICH][OCB][WSTRIDE];

    const int tile = blockIdx.x;   // 0..7 : 4 y-tiles x 2 x-tiles
    const int ocg  = blockIdx.y;   // 0..31
    const int b    = blockIdx.z;   // 0..15
    const int y0 = (tile >> 1) * TILE_H;
    const int x0 = (tile & 1) * TILE_W;

    const int t  = threadIdx.x;
    const int ty = t >> 3;  // 0..31
    const int tx = t & 7;   // 0..7

    const float conv_scale = 1.0f / 48.0f;  // 1/sqrt(256*9)

    float acc[OCB][8];
#pragma unroll
    for (int o = 0; o < OCB; ++o)
#pragma unroll
        for (int j = 0; j < 8; ++j) acc[o][j] = 0.f;

    const float* xb = x + (size_t)b * IN_CH * HH * HH;
    const float* stb = style + b * IN_CH;
    const float* dfb = dfac + b * OUT_CH;

    for (int ic0 = 0; ic0 < IN_CH; ic0 += ICH) {
        __syncthreads();  // protect LDS reuse from previous compute phase
        // ---- stage x halo tiles for ICH input channels ----
        for (int icl = 0; icl < ICH; ++icl) {
            const float* xc = xb + (size_t)(ic0 + icl) * HH * HH;
            for (int s = t; s < XS_ROWS * XS_COLS; s += 256) {
                int row = s / XS_COLS;
                int col = s - row * XS_COLS;
                int gy = y0 + row - 1;
                int gx = x0 + col - 1;
                float v = 0.f;
                if (gy >= 0 && gy < HH && gx >= 0 && gx < HH) v = xc[gy * HH + gx];
                xs[icl][row * XS_STRIDE + col] = v;
            }
        }
        // ---- stage modulated+demodulated weights: ICH*OCB*9 = 288 values ----
        for (int s = t; s < ICH * OCB * 9; s += 256) {
            int icl = s / (OCB * 9);
            int rem = s - icl * (OCB * 9);
            int o   = rem / 9;
            int r   = rem - o * 9;
            int oc  = ocg * OCB + o;
            int ic  = ic0 + icl;
            float wv = weight[((size_t)oc * IN_CH + ic) * 9 + r];
            wmod[icl][o][r] = wv * (conv_scale * stb[ic] * dfb[oc]);
        }
        __syncthreads();
        // ---- compute ----
#pragma unroll 1
        for (int icl = 0; icl < ICH; ++icl) {
            float xr[3][10];
#pragma unroll
            for (int dy = 0; dy < 3; ++dy) {
                const float* p = &xs[icl][(ty + dy) * XS_STRIDE + 8 * tx];
                float4 a  = *(const float4*)(p);
                float4 bv = *(const float4*)(p + 4);
                float2 c  = *(const float2*)(p + 8);
                xr[dy][0] = a.x;  xr[dy][1] = a.y;  xr[dy][2] = a.z;  xr[dy][3] = a.w;
                xr[dy][4] = bv.x; xr[dy][5] = bv.y; xr[dy][6] = bv.z; xr[dy][7] = bv.w;
                xr[dy][8] = c.x;  xr[dy][9] = c.y;
            }
#pragma unroll
            for (int o = 0; o < OCB; ++o) {
                const float* wp = wmod[icl][o];
                float w0 = wp[0], w1 = wp[1], w2 = wp[2];
                float w3 = wp[3], w4 = wp[4], w5 = wp[5];
                float w6 = wp[6], w7 = wp[7], w8 = wp[8];
#pragma unroll
                for (int j = 0; j < 8; ++j) {
                    acc[o][j] += w0 * xr[0][j]     + w1 * xr[0][j + 1] + w2 * xr[0][j + 2]
                               + w3 * xr[1][j]     + w4 * xr[1][j + 1] + w5 * xr[1][j + 2]
                               + w6 * xr[2][j]     + w7 * xr[2][j + 1] + w8 * xr[2][j + 2];
                }
            }
        }
    }

    // ---- write output ----
    const int gy = y0 + ty;
    const int gx = x0 + 8 * tx;
#pragma unroll
    for (int o = 0; o < OCB; ++o) {
        int oc = ocg * OCB + o;
        float* op = out + (((size_t)b * OUT_CH + oc) * HH + gy) * HH + gx;
        float4 v0 = {acc[o][0], acc[o][1], acc[o][2], acc[o][3]};
        float4 v1 = {acc[o][4], acc[o][5], acc[o][6], acc[o][7]};
        *(float4*)(op)     = v0;
        *(float4*)(op + 4) = v1;
    }
}

// ---------------------------------------------------------------------------
extern "C" void kernel_launch(void* const* d_in, const int* in_sizes, int n_in,
                              void* d_out, int out_size, void* d_ws, size_t ws_size,
                              hipStream_t stream) {
    const float* x          = (const float*)d_in[0];  // [16,256,128,128]
    const float* w          = (const float*)d_in[1];  // [16,512]
    const float* weight     = (const float*)d_in[2];  // [1,256,256,3,3]
    const float* mod_weight = (const float*)d_in[3];  // [256,512]
    const float* mod_bias   = (const float*)d_in[4];  // [256]
    float* out = (float*)d_out;

    float* style = (float*)d_ws;                       // [16,256]
    float* dfac  = style + BATCH * IN_CH;              // [16,256]

    style_kernel<<<dim3(BATCH), dim3(256), 0, stream>>>(w, mod_weight, mod_bias, style);
    demod_kernel<<<dim3(BATCH), dim3(256), 0, stream>>>(weight, style, dfac);
    conv_kernel<<<dim3(8, 32, BATCH), dim3(256), 0, stream>>>(x, weight, style, dfac, out);
}

// Round 2
// 833.780 us; speedup vs baseline: 10.4124x; 10.4124x over previous
//
#include <hip/hip_runtime.h>
#include <math.h>

// Problem constants
#define IN_CH  256
#define OUT_CH 256
#define WDIM   512
#define BATCH  16
#define HH     128

typedef _Float16 f16;
typedef f16   f16x8 __attribute__((ext_vector_type(8)));
typedef float f32x4 __attribute__((ext_vector_type(4)));

#define NCOL 130   // 128 data cols + 2 halo cols (zero)

// wmod_g layout: [b][dydx 9][ocg 2][chunk 8][oc 128][ic 32] f16  (4096 f16 = 8KB blocks)
__device__ __host__ inline size_t wblock(int b, int dydx, int ocg, int chunk) {
    return ((((size_t)b * 9 + dydx) * 2 + ocg) * 8 + chunk) * 4096;
}

// ---------------------------------------------------------------------------
// Kernel 1: style[b][i] = (w[b] . mod_weight[i]) * mod_scale + bias[i]
// ---------------------------------------------------------------------------
__global__ void style_kernel(const float* __restrict__ w,
                             const float* __restrict__ mod_weight,
                             const float* __restrict__ mod_bias,
                             float* __restrict__ style) {
    const int b = blockIdx.x;
    const int i = threadIdx.x;
    __shared__ float wsh[WDIM];
    for (int j = threadIdx.x; j < WDIM; j += 256) wsh[j] = w[b * WDIM + j];
    __syncthreads();
    const float mod_scale = 1.0f / sqrtf((float)WDIM);
    float acc = 0.f;
    const float* mwp = mod_weight + (size_t)i * WDIM;
    for (int j = 0; j < WDIM; ++j) acc += wsh[j] * mwp[j];
    style[b * IN_CH + i] = acc * mod_scale + mod_bias[i];
}

// ---------------------------------------------------------------------------
// Kernel 2: dfac[b][o] = rsqrt( (1/2304) * sum_i style^2 * sum_r w^2 + 1e-8 )
// ---------------------------------------------------------------------------
__global__ void demod_kernel(const float* __restrict__ weight,
                             const float* __restrict__ style,
                             float* __restrict__ dfac) {
    const int b = blockIdx.x;
    const int o = threadIdx.x;
    __shared__ float s2[IN_CH];
    for (int j = threadIdx.x; j < IN_CH; j += 256) {
        float s = style[b * IN_CH + j];
        s2[j] = s * s;
    }
    __syncthreads();
    const float conv_scale2 = 1.0f / 2304.0f;
    float acc = 0.f;
    const float* wp = weight + (size_t)o * IN_CH * 9;
    for (int i = 0; i < IN_CH; ++i) {
        float sq = 0.f;
#pragma unroll
        for (int r = 0; r < 9; ++r) { float v = wp[i * 9 + r]; sq += v * v; }
        acc += sq * s2[i];
    }
    dfac[b * OUT_CH + o] = rsqrtf(acc * conv_scale2 + 1e-8f);
}

// ---------------------------------------------------------------------------
// Kernel 3: wmod_g[b][dydx][ocg][chunk][oc][ic] (f16) = conv_scale*w*style*dfac
// ---------------------------------------------------------------------------
__global__ void wmod_kernel(const float* __restrict__ weight,
                            const float* __restrict__ style,
                            const float* __restrict__ dfac,
                            f16* __restrict__ wmod) {
    const int oc = blockIdx.x;   // 256
    const int b  = blockIdx.y;   // 16
    const int ic = threadIdx.x;  // 256
    const float sd = style[b * IN_CH + ic] * (1.0f / 48.0f) * dfac[b * OUT_CH + oc];
    const float* wp = weight + ((size_t)oc * IN_CH + ic) * 9;
    const int ocg = oc >> 7, ocl = oc & 127;
    const int chunk = ic >> 5, icl = ic & 31;
#pragma unroll
    for (int r = 0; r < 9; ++r) {
        f16 h = (f16)(wp[r] * sd);
        wmod[wblock(b, r, ocg, chunk) + (size_t)ocl * 32 + icl] = h;
    }
}

// ---------------------------------------------------------------------------
// Kernel 4: implicit-GEMM modulated conv via mfma_f32_16x16x32_f16.
// Block: 256 thr = 4 waves; tile M=128 oc x N=128 cols (one y row).
// Wave (wm,wn): 64x64 via 4x4 frags of 16x16, acc[4][4] f32x4.
// LDS X tile: [3 rows][130 cols][32 ic] f16, 64B per (r,c), line-rot swizzle.
// ---------------------------------------------------------------------------
__global__ __launch_bounds__(256, 3) void conv_mfma(
        const float* __restrict__ x,
        const f16*  __restrict__ wmod,
        float* __restrict__ out) {
    __shared__ uint4 xs4[3 * NCOL * 4];     // 24960 B
    __shared__ uint4 wls4[2][512];          // 2 x 8192 B

    const int y0  = blockIdx.x;   // 0..127
    const int ocg = blockIdx.y;   // 0..1
    const int b   = blockIdx.z;   // 0..15

    const int t  = threadIdx.x;
    const int l  = t & 63;
    const int w  = t >> 6;
    const int wm = w >> 1, wn = w & 1;
    const int lm = l & 15, lg = l >> 4;

    f32x4 acc[4][4];
#pragma unroll
    for (int i = 0; i < 4; ++i)
#pragma unroll
        for (int j = 0; j < 4; ++j) acc[i][j] = (f32x4){0.f, 0.f, 0.f, 0.f};

    // zero halo columns (c=0 and c=129) once: 6 blocks of 64B = 24 x 16B
    if (t < 24) {
        int blk = t >> 2;
        int r = blk >> 1;
        int c = (blk & 1) ? 129 : 0;
        uint4 z = {0u, 0u, 0u, 0u};
        xs4[(r * NCOL + c) * 4 + (t & 3)] = z;
    }

    const int cq = t & 31;   // col-quad: cols 1+4cq .. 1+4cq+3
    const int gq = t >> 5;   // ic-quad:  ics  4gq .. 4gq+3

    // ---- X stage for a chunk ----
    auto stageX = [&](int chunk) {
        const int ic0 = chunk * 32;
#pragma unroll
        for (int r = 0; r < 3; ++r) {
            const int gy = y0 - 1 + r;
            float vv[4][4];  // [rr][cc]
            if (gy >= 0 && gy < HH) {
#pragma unroll
                for (int rr = 0; rr < 4; ++rr) {
                    const float* gp = x + (((size_t)(b * IN_CH + ic0 + 4 * gq + rr)) * HH + gy) * HH + 4 * cq;
                    float4 q = *(const float4*)gp;
                    vv[rr][0] = q.x; vv[rr][1] = q.y; vv[rr][2] = q.z; vv[rr][3] = q.w;
                }
            } else {
#pragma unroll
                for (int rr = 0; rr < 4; ++rr)
#pragma unroll
                    for (int cc = 0; cc < 4; ++cc) vv[rr][cc] = 0.f;
            }
#pragma unroll
            for (int cc = 0; cc < 4; ++cc) {
                const int c = 1 + 4 * cq + cc;
                const int lsel = ((gq >> 1) + (c >> 2)) & 3;
                union { f16 h[4]; uint2 u2; } pk;
                pk.h[0] = (f16)vv[0][cc]; pk.h[1] = (f16)vv[1][cc];
                pk.h[2] = (f16)vv[2][cc]; pk.h[3] = (f16)vv[3][cc];
                char* p = (char*)xs4 + (((size_t)r * NCOL + c) << 6) + (lsel << 4) + ((gq & 1) << 3);
                *(uint2*)p = pk.u2;
            }
        }
    };

    // prologue: W(chunk0,dydx0) -> wls[0]; X chunk0
    {
        const uint4* g = (const uint4*)(wmod + wblock(b, 0, ocg, 0));
        wls4[0][t]       = g[t];
        wls4[0][t + 256] = g[t + 256];
    }
    stageX(0);
    __syncthreads();

    int cur = 0;
    for (int chunk = 0; chunk < 8; ++chunk) {
        for (int dydx = 0; dydx < 9; ++dydx) {
            // prefetch next W block into registers (lands during MFMA)
            const bool hasnext = !(chunk == 7 && dydx == 8);
            int nd = dydx + 1, nb = chunk;
            if (nd == 9) { nd = 0; nb = chunk + 1; }
            uint4 p0, p1;
            if (hasnext) {
                const uint4* g = (const uint4*)(wmod + wblock(b, nd, ocg, nb));
                p0 = g[t]; p1 = g[t + 256];
            }

            const int dy = dydx / 3;
            const int dx = dydx - 3 * dy;

            // A fragments: wls[cur], oc-local row = wm*64 + mt*16 + lm, 16B line lg
            f16x8 af[4];
#pragma unroll
            for (int mt = 0; mt < 4; ++mt) {
                const int ocl = wm * 64 + mt * 16 + lm;
                const char* ap = (const char*)wls4[cur] + ((size_t)ocl << 6) + (lg << 4);
                af[mt] = *(const f16x8*)ap;
            }
#pragma unroll
            for (int nt = 0; nt < 4; ++nt) {
                const int c = wn * 64 + nt * 16 + lm + dx;   // 0..129
                const int lsel = (lg + (c >> 2)) & 3;
                const char* bp = (const char*)xs4 + (((size_t)dy * NCOL + c) << 6) + (lsel << 4);
                f16x8 bf = *(const f16x8*)bp;
#pragma unroll
                for (int mt = 0; mt < 4; ++mt) {
                    acc[mt][nt] = __builtin_amdgcn_mfma_f32_16x16x32_f16(af[mt], bf, acc[mt][nt], 0, 0, 0);
                }
            }

            if (hasnext) {
                uint4* d = wls4[cur ^ 1];
                d[t] = p0; d[t + 256] = p1;
            }
            __syncthreads();
            cur ^= 1;
        }
        if (chunk < 7) {
            stageX(chunk + 1);
            __syncthreads();
        }
    }

    // epilogue: D row = oc (ocg*128 + wm*64 + mt*16 + lg*4 + reg), col = spatial
#pragma unroll
    for (int mt = 0; mt < 4; ++mt) {
#pragma unroll
        for (int nt = 0; nt < 4; ++nt) {
            const int col = wn * 64 + nt * 16 + lm;
#pragma unroll
            for (int reg = 0; reg < 4; ++reg) {
                const int oc = ocg * 128 + wm * 64 + mt * 16 + lg * 4 + reg;
                out[(((size_t)(b * OUT_CH + oc)) * HH + y0) * HH + col] = acc[mt][nt][reg];
            }
        }
    }
}

// ---------------------------------------------------------------------------
// Fallback fp32 direct conv (round-1, proven correct) used if ws too small.
// ---------------------------------------------------------------------------
#define TILE_H 32
#define TILE_W 64
#define OCB    8
#define ICH    4
#define XS_COLS 66
#define XS_STRIDE 68
#define XS_ROWS 34

__global__ __launch_bounds__(256, 3) void conv_kernel(
        const float* __restrict__ x,
        const float* __restrict__ weight,
        const float* __restrict__ style,
        const float* __restrict__ dfac,
        float* __restrict__ out) {
    __shared__ float xs[ICH][XS_ROWS * XS_STRIDE];
    __shared__ float wmod[ICH][OCB][12];

    const int tile = blockIdx.x;
    const int ocg  = blockIdx.y;
    const int b    = blockIdx.z;
    const int y0 = (tile >> 1) * TILE_H;
    const int x0 = (tile & 1) * TILE_W;

    const int t  = threadIdx.x;
    const int ty = t >> 3;
    const int tx = t & 7;

    const float conv_scale = 1.0f / 48.0f;

    float acc[OCB][8];
#pragma unroll
    for (int o = 0; o < OCB; ++o)
#pragma unroll
        for (int j = 0; j < 8; ++j) acc[o][j] = 0.f;

    const float* xb = x + (size_t)b * IN_CH * HH * HH;
    const float* stb = style + b * IN_CH;
    const float* dfb = dfac + b * OUT_CH;

    for (int ic0 = 0; ic0 < IN_CH; ic0 += ICH) {
        __syncthreads();
        for (int icl = 0; icl < ICH; ++icl) {
            const float* xc = xb + (size_t)(ic0 + icl) * HH * HH;
            for (int s = t; s < XS_ROWS * XS_COLS; s += 256) {
                int row = s / XS_COLS;
                int col = s - row * XS_COLS;
                int gy = y0 + row - 1;
                int gx = x0 + col - 1;
                float v = 0.f;
                if (gy >= 0 && gy < HH && gx >= 0 && gx < HH) v = xc[gy * HH + gx];
                xs[icl][row * XS_STRIDE + col] = v;
            }
        }
        for (int s = t; s < ICH * OCB * 9; s += 256) {
            int icl = s / (OCB * 9);
            int rem = s - icl * (OCB * 9);
            int o   = rem / 9;
            int r   = rem - o * 9;
            int oc  = ocg * OCB + o;
            int ic  = ic0 + icl;
            float wv = weight[((size_t)oc * IN_CH + ic) * 9 + r];
            wmod[icl][o][r] = wv * (conv_scale * stb[ic] * dfb[oc]);
        }
        __syncthreads();
#pragma unroll 1
        for (int icl = 0; icl < ICH; ++icl) {
            float xr[3][10];
#pragma unroll
            for (int dy = 0; dy < 3; ++dy) {
                const float* p = &xs[icl][(ty + dy) * XS_STRIDE + 8 * tx];
                float4 a  = *(const float4*)(p);
                float4 bv = *(const float4*)(p + 4);
                float2 c  = *(const float2*)(p + 8);
                xr[dy][0] = a.x;  xr[dy][1] = a.y;  xr[dy][2] = a.z;  xr[dy][3] = a.w;
                xr[dy][4] = bv.x; xr[dy][5] = bv.y; xr[dy][6] = bv.z; xr[dy][7] = bv.w;
                xr[dy][8] = c.x;  xr[dy][9] = c.y;
            }
#pragma unroll
            for (int o = 0; o < OCB; ++o) {
                const float* wp = wmod[icl][o];
                float w0 = wp[0], w1 = wp[1], w2 = wp[2];
                float w3 = wp[3], w4 = wp[4], w5 = wp[5];
                float w6 = wp[6], w7 = wp[7], w8 = wp[8];
#pragma unroll
                for (int j = 0; j < 8; ++j) {
                    acc[o][j] += w0 * xr[0][j]     + w1 * xr[0][j + 1] + w2 * xr[0][j + 2]
                               + w3 * xr[1][j]     + w4 * xr[1][j + 1] + w5 * xr[1][j + 2]
                               + w6 * xr[2][j]     + w7 * xr[2][j + 1] + w8 * xr[2][j + 2];
                }
            }
        }
    }

    const int gy = y0 + ty;
    const int gx = x0 + 8 * tx;
#pragma unroll
    for (int o = 0; o < OCB; ++o) {
        int oc = ocg * OCB + o;
        float* op = out + (((size_t)b * OUT_CH + oc) * HH + gy) * HH + gx;
        float4 v0 = {acc[o][0], acc[o][1], acc[o][2], acc[o][3]};
        float4 v1 = {acc[o][4], acc[o][5], acc[o][6], acc[o][7]};
        *(float4*)(op)     = v0;
        *(float4*)(op + 4) = v1;
    }
}

// ---------------------------------------------------------------------------
extern "C" void kernel_launch(void* const* d_in, const int* in_sizes, int n_in,
                              void* d_out, int out_size, void* d_ws, size_t ws_size,
                              hipStream_t stream) {
    const float* x          = (const float*)d_in[0];
    const float* w          = (const float*)d_in[1];
    const float* weight     = (const float*)d_in[2];
    const float* mod_weight = (const float*)d_in[3];
    const float* mod_bias   = (const float*)d_in[4];
    float* out = (float*)d_out;

    float* style = (float*)d_ws;                 // 4096 floats
    float* dfac  = style + BATCH * IN_CH;        // 4096 floats

    style_kernel<<<dim3(BATCH), dim3(256), 0, stream>>>(w, mod_weight, mod_bias, style);
    demod_kernel<<<dim3(BATCH), dim3(256), 0, stream>>>(weight, style, dfac);

    const size_t need = 32768 + (size_t)BATCH * 9 * 2 * 8 * 4096 * sizeof(f16);
    if (ws_size >= need) {
        f16* wmodp = (f16*)((char*)d_ws + 32768);
        wmod_kernel<<<dim3(256, BATCH), dim3(256), 0, stream>>>(weight, style, dfac, wmodp);
        conv_mfma<<<dim3(128, 2, BATCH), dim3(256), 0, stream>>>(x, wmodp, out);
    } else {
        conv_kernel<<<dim3(8, 32, BATCH), dim3(256), 0, stream>>>(x, weight, style, dfac, out);
    }
}

// Round 3
// 778.382 us; speedup vs baseline: 11.1535x; 1.0712x over previous
//
#include <hip/hip_runtime.h>
#include <math.h>

// Problem constants
#define IN_CH  256
#define OUT_CH 256
#define WDIM   512
#define BATCH  16
#define HH     128

typedef _Float16 f16;
typedef f16   f16x8 __attribute__((ext_vector_type(8)));
typedef float f32x4 __attribute__((ext_vector_type(4)));

#define NCOL 130   // 128 data cols + 2 halo cols (zero)
#define XSLOTS (3 * NCOL * 4)   // uint4 slots per X buffer

// wmod layout: [b][dydx 9][ocg 2][chunk 8][oc 128][ic 32] f16 (4096 f16 = 8KB blocks)
__device__ __host__ inline size_t wblock(int b, int dydx, int ocg, int chunk) {
    return ((((size_t)b * 9 + dydx) * 2 + ocg) * 8 + chunk) * 4096;
}

// ---------------------------------------------------------------------------
// style[b][i] = (w[b] . mod_weight[i]) * mod_scale + bias[i]
// grid (4, 16), 64 threads
// ---------------------------------------------------------------------------
__global__ void style_kernel(const float* __restrict__ w,
                             const float* __restrict__ mod_weight,
                             const float* __restrict__ mod_bias,
                             float* __restrict__ style) {
    const int b = blockIdx.y;
    const int i = blockIdx.x * 64 + threadIdx.x;
    const float4* wp = (const float4*)(w + (size_t)b * WDIM);
    const float4* mp = (const float4*)(mod_weight + (size_t)i * WDIM);
    float acc = 0.f;
#pragma unroll 8
    for (int j = 0; j < WDIM / 4; ++j) {
        float4 a = wp[j], c = mp[j];
        acc += a.x * c.x + a.y * c.y + a.z * c.z + a.w * c.w;
    }
    style[b * IN_CH + i] = acc * (1.0f / sqrtf((float)WDIM)) + mod_bias[i];
}

// ---------------------------------------------------------------------------
// q[o][i] = sum_r weight[o,i,r]^2.  grid 256, 256 threads
// ---------------------------------------------------------------------------
__global__ void wsq_kernel(const float* __restrict__ weight,
                           float* __restrict__ q) {
    const int o = blockIdx.x, i = threadIdx.x;
    const float* wp = weight + ((size_t)o * IN_CH + i) * 9;
    float s = 0.f;
#pragma unroll
    for (int r = 0; r < 9; ++r) { float v = wp[r]; s += v * v; }
    q[o * IN_CH + i] = s;
}

// ---------------------------------------------------------------------------
// dfac[b][o] = rsqrt((1/2304) * sum_i style^2 * q + 1e-8). grid (256,16), 64thr
// ---------------------------------------------------------------------------
__global__ void demod_kernel(const float* __restrict__ q,
                             const float* __restrict__ style,
                             float* __restrict__ dfac) {
    const int o = blockIdx.x, b = blockIdx.y, t = threadIdx.x;
    float4 qv = *(const float4*)(q + (size_t)o * IN_CH + 4 * t);
    float4 sv = *(const float4*)(style + (size_t)b * IN_CH + 4 * t);
    float s = qv.x * sv.x * sv.x + qv.y * sv.y * sv.y
            + qv.z * sv.z * sv.z + qv.w * sv.w * sv.w;
#pragma unroll
    for (int off = 32; off > 0; off >>= 1) s += __shfl_down(s, off, 64);
    if (t == 0) dfac[b * OUT_CH + o] = rsqrtf(s * (1.0f / 2304.0f) + 1e-8f);
}

// ---------------------------------------------------------------------------
// wmod[b][r][ocg][chunk][ocl][icl] f16, coalesced 32B stores.
// grid (9, 2, 16), 256 threads
// ---------------------------------------------------------------------------
__global__ void wmod_kernel(const float* __restrict__ weight,
                            const float* __restrict__ style,
                            const float* __restrict__ dfac,
                            f16* __restrict__ wmod) {
    const int r = blockIdx.x, ocg = blockIdx.y, b = blockIdx.z;
    const int t = threadIdx.x;
    const int ocl = t >> 1, half = t & 1;
    const int oc = ocg * 128 + ocl;
    const float sd = dfac[b * OUT_CH + oc] * (1.0f / 48.0f);
    const float* wp = weight + (size_t)oc * IN_CH * 9 + r;
    const float* sp = style + (size_t)b * IN_CH;
    for (int chunk = 0; chunk < 8; ++chunk) {
        const int icb = chunk * 32 + half * 16;
        union { f16 h[16]; uint4 u[2]; } buf;
#pragma unroll
        for (int j = 0; j < 16; ++j) {
            const int ic = icb + j;
            buf.h[j] = (f16)(wp[(size_t)ic * 9] * sp[ic] * sd);
        }
        uint4* dst = (uint4*)(wmod + wblock(b, r, ocg, chunk) + (size_t)ocl * 32 + half * 16);
        dst[0] = buf.u[0];
        dst[1] = buf.u[1];
    }
}

// ---------------------------------------------------------------------------
// Implicit-GEMM modulated conv via mfma_f32_16x16x32_f16.
// Block: 256 thr = 4 waves; tile M=128 oc x N=128 cols (one y row).
// A-fragments loaded DIRECTLY from global (L2-resident), 1-dydx-ahead
// register prefetch. X double-buffered in LDS. ONE barrier per ic-chunk
// (144 MFMA between barriers).
// ---------------------------------------------------------------------------
__global__ __launch_bounds__(256, 3) void conv_mfma(
        const float* __restrict__ x,
        const f16*  __restrict__ wmod,
        float* __restrict__ out) {
    __shared__ uint4 xs4[2 * XSLOTS];    // 2 x 24960 B

    // bijective XCD-chunk swizzle: 4096 blocks, 8 XCDs, 512 logical per XCD
    const int bid = blockIdx.x;
    const int lid = (bid & 7) * 512 + (bid >> 3);
    const int ocg = lid & 1;          // ocg pair adjacent -> same XCD L2
    const int y0  = (lid >> 1) & 127; // adjacent y share 2/3 x-rows
    const int b   = lid >> 8;

    const int t  = threadIdx.x;
    const int l  = t & 63;
    const int w  = t >> 6;
    const int wm = w >> 1, wn = w & 1;
    const int lm = l & 15, lg = l >> 4;

    f32x4 acc[4][4];
#pragma unroll
    for (int i = 0; i < 4; ++i)
#pragma unroll
        for (int j = 0; j < 4; ++j) acc[i][j] = (f32x4){0.f, 0.f, 0.f, 0.f};

    // zero halo cols (c=0,129) in BOTH buffers: 2 buf x 3 r x 2 c x 4 slots
    if (t < 48) {
        int buf = t / 24, rem = t - 24 * buf;
        int blk = rem >> 2;
        int r = blk >> 1;
        int c = (blk & 1) ? 129 : 0;
        uint4 z = {0u, 0u, 0u, 0u};
        xs4[buf * XSLOTS + (r * NCOL + c) * 4 + (rem & 3)] = z;
    }

    const int cq = t & 31;   // col-quad: cols 1+4cq..+3
    const int gq = t >> 5;   // ic-quad:  ics 4gq..+3

    auto stageX = [&](int chunk, int buf) {
        const int ic0 = chunk * 32;
        uint4* xbuf = xs4 + buf * XSLOTS;
#pragma unroll
        for (int r = 0; r < 3; ++r) {
            const int gy = y0 - 1 + r;
            float vv[4][4];
            if (gy >= 0 && gy < HH) {
#pragma unroll
                for (int rr = 0; rr < 4; ++rr) {
                    const float* gp = x + (((size_t)(b * IN_CH + ic0 + 4 * gq + rr)) * HH + gy) * HH + 4 * cq;
                    float4 qv = *(const float4*)gp;
                    vv[rr][0] = qv.x; vv[rr][1] = qv.y; vv[rr][2] = qv.z; vv[rr][3] = qv.w;
                }
            } else {
#pragma unroll
                for (int rr = 0; rr < 4; ++rr)
#pragma unroll
                    for (int cc = 0; cc < 4; ++cc) vv[rr][cc] = 0.f;
            }
#pragma unroll
            for (int cc = 0; cc < 4; ++cc) {
                const int c = 1 + 4 * cq + cc;
                const int lsel = ((gq >> 1) + (c >> 2)) & 3;
                union { f16 h[4]; uint2 u2; } pk;
                pk.h[0] = (f16)vv[0][cc]; pk.h[1] = (f16)vv[1][cc];
                pk.h[2] = (f16)vv[2][cc]; pk.h[3] = (f16)vv[3][cc];
                char* p = (char*)xbuf + (((size_t)r * NCOL + c) << 6) + (lsel << 4) + ((gq & 1) << 3);
                *(uint2*)p = pk.u2;
            }
        }
    };

    // A-fragment global load (coalesced 16B/lane, L2-resident)
    auto aload = [&](int chunk, int dydx, f16x8* dst) {
        const f16* p = wmod + wblock(b, dydx, ocg, chunk);
#pragma unroll
        for (int mt = 0; mt < 4; ++mt) {
            const int ocl = wm * 64 + mt * 16 + lm;
            dst[mt] = *(const f16x8*)(p + (size_t)ocl * 32 + lg * 8);
        }
    };

    f16x8 afc[4], afn[4];
    aload(0, 0, afc);
    stageX(0, 0);
    __syncthreads();

    int cur = 0;
    for (int chunk = 0; chunk < 8; ++chunk) {
        if (chunk < 7) stageX(chunk + 1, cur ^ 1);
        const uint4* xbuf = xs4 + cur * XSLOTS;
#pragma unroll
        for (int dydx = 0; dydx < 9; ++dydx) {
            int nd = dydx + 1, nb = chunk;
            if (nd == 9) { nd = 0; nb = chunk + 1; }
            if (nb < 8) aload(nb, nd, afn);

            const int dy = dydx / 3;
            const int dx = dydx - 3 * dy;
#pragma unroll
            for (int nt = 0; nt < 4; ++nt) {
                const int c = wn * 64 + nt * 16 + lm + dx;
                const int lsel = (lg + (c >> 2)) & 3;
                const char* bp = (const char*)xbuf + (((size_t)dy * NCOL + c) << 6) + (lsel << 4);
                f16x8 bf = *(const f16x8*)bp;
#pragma unroll
                for (int mt = 0; mt < 4; ++mt) {
                    acc[mt][nt] = __builtin_amdgcn_mfma_f32_16x16x32_f16(afc[mt], bf, acc[mt][nt], 0, 0, 0);
                }
            }
#pragma unroll
            for (int mt = 0; mt < 4; ++mt) afc[mt] = afn[mt];
        }
        __syncthreads();
        cur ^= 1;
    }

    // epilogue: row oc = ocg*128 + wm*64 + mt*16 + lg*4 + reg, col = spatial
#pragma unroll
    for (int mt = 0; mt < 4; ++mt) {
#pragma unroll
        for (int nt = 0; nt < 4; ++nt) {
            const int col = wn * 64 + nt * 16 + lm;
#pragma unroll
            for (int reg = 0; reg < 4; ++reg) {
                const int oc = ocg * 128 + wm * 64 + mt * 16 + lg * 4 + reg;
                out[(((size_t)(b * OUT_CH + oc)) * HH + y0) * HH + col] = acc[mt][nt][reg];
            }
        }
    }
}

// ---------------------------------------------------------------------------
// Fallback fp32 direct conv (round-1, proven correct) used if ws too small.
// ---------------------------------------------------------------------------
#define TILE_H 32
#define TILE_W 64
#define OCB    8
#define ICH    4
#define XS_COLS 66
#define XS_STRIDE 68
#define XS_ROWS 34

__global__ void demod_fb_kernel(const float* __restrict__ weight,
                                const float* __restrict__ style,
                                float* __restrict__ dfac) {
    const int b = blockIdx.x;
    const int o = threadIdx.x;
    __shared__ float s2[IN_CH];
    for (int j = threadIdx.x; j < IN_CH; j += 256) {
        float s = style[b * IN_CH + j];
        s2[j] = s * s;
    }
    __syncthreads();
    float acc2 = 0.f;
    const float* wp = weight + (size_t)o * IN_CH * 9;
    for (int i = 0; i < IN_CH; ++i) {
        float sq = 0.f;
#pragma unroll
        for (int r = 0; r < 9; ++r) { float v = wp[i * 9 + r]; sq += v * v; }
        acc2 += sq * s2[i];
    }
    dfac[b * OUT_CH + o] = rsqrtf(acc2 * (1.0f / 2304.0f) + 1e-8f);
}

__global__ __launch_bounds__(256, 3) void conv_kernel(
        const float* __restrict__ x,
        const float* __restrict__ weight,
        const float* __restrict__ style,
        const float* __restrict__ dfac,
        float* __restrict__ out) {
    __shared__ float xs[ICH][XS_ROWS * XS_STRIDE];
    __shared__ float wsm[ICH][OCB][12];

    const int tile = blockIdx.x;
    const int ocg  = blockIdx.y;
    const int b    = blockIdx.z;
    const int y0 = (tile >> 1) * TILE_H;
    const int x0 = (tile & 1) * TILE_W;

    const int t  = threadIdx.x;
    const int ty = t >> 3;
    const int tx = t & 7;

    float acc[OCB][8];
#pragma unroll
    for (int o = 0; o < OCB; ++o)
#pragma unroll
        for (int j = 0; j < 8; ++j) acc[o][j] = 0.f;

    const float* xb = x + (size_t)b * IN_CH * HH * HH;
    const float* stb = style + b * IN_CH;
    const float* dfb = dfac + b * OUT_CH;

    for (int ic0 = 0; ic0 < IN_CH; ic0 += ICH) {
        __syncthreads();
        for (int icl = 0; icl < ICH; ++icl) {
            const float* xc = xb + (size_t)(ic0 + icl) * HH * HH;
            for (int s = t; s < XS_ROWS * XS_COLS; s += 256) {
                int row = s / XS_COLS;
                int col = s - row * XS_COLS;
                int gy = y0 + row - 1;
                int gx = x0 + col - 1;
                float v = 0.f;
                if (gy >= 0 && gy < HH && gx >= 0 && gx < HH) v = xc[gy * HH + gx];
                xs[icl][row * XS_STRIDE + col] = v;
            }
        }
        for (int s = t; s < ICH * OCB * 9; s += 256) {
            int icl = s / (OCB * 9);
            int rem = s - icl * (OCB * 9);
            int o   = rem / 9;
            int r   = rem - o * 9;
            int oc  = ocg * OCB + o;
            int ic  = ic0 + icl;
            float wv = weight[((size_t)oc * IN_CH + ic) * 9 + r];
            wsm[icl][o][r] = wv * ((1.0f / 48.0f) * stb[ic] * dfb[oc]);
        }
        __syncthreads();
#pragma unroll 1
        for (int icl = 0; icl < ICH; ++icl) {
            float xr[3][10];
#pragma unroll
            for (int dy = 0; dy < 3; ++dy) {
                const float* p = &xs[icl][(ty + dy) * XS_STRIDE + 8 * tx];
                float4 a  = *(const float4*)(p);
                float4 bv = *(const float4*)(p + 4);
                float2 c  = *(const float2*)(p + 8);
                xr[dy][0] = a.x;  xr[dy][1] = a.y;  xr[dy][2] = a.z;  xr[dy][3] = a.w;
                xr[dy][4] = bv.x; xr[dy][5] = bv.y; xr[dy][6] = bv.z; xr[dy][7] = bv.w;
                xr[dy][8] = c.x;  xr[dy][9] = c.y;
            }
#pragma unroll
            for (int o = 0; o < OCB; ++o) {
                const float* wp = wsm[icl][o];
                float w0 = wp[0], w1 = wp[1], w2 = wp[2];
                float w3 = wp[3], w4 = wp[4], w5 = wp[5];
                float w6 = wp[6], w7 = wp[7], w8 = wp[8];
#pragma unroll
                for (int j = 0; j < 8; ++j) {
                    acc[o][j] += w0 * xr[0][j]     + w1 * xr[0][j + 1] + w2 * xr[0][j + 2]
                               + w3 * xr[1][j]     + w4 * xr[1][j + 1] + w5 * xr[1][j + 2]
                               + w6 * xr[2][j]     + w7 * xr[2][j + 1] + w8 * xr[2][j + 2];
                }
            }
        }
    }

    const int gy = y0 + ty;
    const int gx = x0 + 8 * tx;
#pragma unroll
    for (int o = 0; o < OCB; ++o) {
        int oc = ocg * OCB + o;
        float* op = out + (((size_t)b * OUT_CH + oc) * HH + gy) * HH + gx;
        float4 v0 = {acc[o][0], acc[o][1], acc[o][2], acc[o][3]};
        float4 v1 = {acc[o][4], acc[o][5], acc[o][6], acc[o][7]};
        *(float4*)(op)     = v0;
        *(float4*)(op + 4) = v1;
    }
}

// ---------------------------------------------------------------------------
extern "C" void kernel_launch(void* const* d_in, const int* in_sizes, int n_in,
                              void* d_out, int out_size, void* d_ws, size_t ws_size,
                              hipStream_t stream) {
    const float* x          = (const float*)d_in[0];
    const float* w          = (const float*)d_in[1];
    const float* weight     = (const float*)d_in[2];
    const float* mod_weight = (const float*)d_in[3];
    const float* mod_bias   = (const float*)d_in[4];
    float* out = (float*)d_out;

    // ws layout: style 16KB | dfac 16KB | q 256KB | wmod 18.9MB
    float* style = (float*)d_ws;
    float* dfac  = style + BATCH * IN_CH;
    float* q     = dfac + BATCH * OUT_CH;
    f16*   wmodp = (f16*)((char*)d_ws + 16384 + 16384 + 262144);

    const size_t need = 16384 + 16384 + 262144
                      + (size_t)BATCH * 9 * 2 * 8 * 4096 * sizeof(f16);

    style_kernel<<<dim3(4, BATCH), dim3(64), 0, stream>>>(w, mod_weight, mod_bias, style);

    if (ws_size >= need) {
        wsq_kernel<<<dim3(256), dim3(256), 0, stream>>>(weight, q);
        demod_kernel<<<dim3(256, BATCH), dim3(64), 0, stream>>>(q, style, dfac);
        wmod_kernel<<<dim3(9, 2, BATCH), dim3(256), 0, stream>>>(weight, style, dfac, wmodp);
        conv_mfma<<<dim3(4096), dim3(256), 0, stream>>>(x, wmodp, out);
    } else {
        demod_fb_kernel<<<dim3(BATCH), dim3(256), 0, stream>>>(weight, style, dfac);
        conv_kernel<<<dim3(8, 32, BATCH), dim3(256), 0, stream>>>(x, weight, style, dfac, out);
    }
}